// Round 6
// baseline (599.083 us; speedup 1.0000x reference)
//
#include <hip/hip_runtime.h>
#include <stdint.h>

// B=8, CIN=128, COUT=256, H=256, W=256 -> pooled 128x128, out (8,256,128,128) fp32

// Per-oc packed record in ocdata, stride 56 u32 (224 B):
//   [0..35]  packed weight bits: word (t*4+q) = bits of cin 32q..32q+31, tap t
//   [36..44] border corr (as int): case 3*hB+wB; hB 0/1(top)/2(bot), wB 0/1(L)/2(R)
//   [48]     scale, [49] pr_bias0, [50] alpha, [51] pr_bias1  (floats)

// ---------------------------------------------------------------------------
// Kernel 0: weight prep. One block per output channel (256 blocks, 128 thr).
// ---------------------------------------------------------------------------
__global__ __launch_bounds__(128) void wprep_kernel(const float* __restrict__ w,
                                                    const float* __restrict__ pb0,
                                                    const float* __restrict__ alpha,
                                                    const float* __restrict__ pb1,
                                                    uint32_t* __restrict__ ocdata) {
    int oc = blockIdx.x;
    int cin = threadIdx.x;              // 0..127
    const float* wp = w + ((long)oc * 128 + cin) * 9;
    float wk[9];
    float sabs = 0.f;
#pragma unroll
    for (int k = 0; k < 9; ++k) { wk[k] = wp[k]; sabs += fabsf(wk[k]); }
    int gi = cin >> 6;                  // wave id 0/1
    int lane = cin & 63;
    __shared__ float ssum[2];
    __shared__ int spc[2][9];
    for (int off = 32; off > 0; off >>= 1) sabs += __shfl_down(sabs, off, 64);
    if (lane == 0) ssum[gi] = sabs;
    uint32_t* od = ocdata + (size_t)oc * 56;
#pragma unroll
    for (int k = 0; k < 9; ++k) {
        unsigned long long m = __ballot(wk[k] > 0.f);
        if (lane == 0) {
            od[k * 4 + 2 * gi]     = (uint32_t)m;
            od[k * 4 + 2 * gi + 1] = (uint32_t)(m >> 32);
            spc[gi][k] = __popcll(m);
        }
    }
    __syncthreads();
    if (cin == 0) {
        float s = (ssum[0] + ssum[1]) * (1.0f / 1152.0f);
        od[48] = __float_as_uint(s);
        od[49] = __float_as_uint(pb0[oc]);
        od[50] = __float_as_uint(alpha[oc]);
        od[51] = __float_as_uint(pb1[oc]);
        int ct[9];
#pragma unroll
        for (int t = 0; t < 9; ++t) ct[t] = 128 - 2 * (spc[0][t] + spc[1][t]);
        int cT = ct[0] + ct[1] + ct[2];
        int cB = ct[6] + ct[7] + ct[8];
        int cL = ct[0] + ct[3] + ct[6];
        int cR = ct[2] + ct[5] + ct[8];
        od[36 + 0] = (uint32_t)0;                       // interior
        od[36 + 1] = (uint32_t)cL;                      // left
        od[36 + 2] = (uint32_t)cR;                      // right
        od[36 + 3] = (uint32_t)cT;                      // top
        od[36 + 4] = (uint32_t)(cT + cL - ct[0]);       // top-left
        od[36 + 5] = (uint32_t)(cT + cR - ct[2]);       // top-right
        od[36 + 6] = (uint32_t)cB;                      // bottom
        od[36 + 7] = (uint32_t)(cB + cL - ct[6]);       // bottom-left
        od[36 + 8] = (uint32_t)(cB + cR - ct[8]);       // bottom-right
        od[45] = od[46] = od[47] = 0u;
        od[52] = od[53] = od[54] = od[55] = 0u;
    }
}

// ---------------------------------------------------------------------------
// Kernel 1: avgpool 2x2 + bias + sign -> channel-bit-packed activations.
// ---------------------------------------------------------------------------
__global__ __launch_bounds__(256) void pool_pack_kernel(const float* __restrict__ x,
                                                        const float* __restrict__ bias,
                                                        uint32_t* __restrict__ packedA) {
    int h = blockIdx.x;    // pooled row 0..127
    int b = blockIdx.y;    // 0..7
    int tid = threadIdx.x;
    __shared__ float sbias[128];
    __shared__ uint8_t sb[128 * 132];   // [c][w] bytes, row stride 132
    if (tid < 128) sbias[tid] = bias[tid];
    __syncthreads();
    const float4* x4 = reinterpret_cast<const float4*>(x);
#pragma unroll 4
    for (int it = 0; it < 32; ++it) {
        int j = it * 256 + tid;         // [0, 8192)
        int c = j >> 6;                 // 0..127
        int wq = j & 63;                // float4 col -> output pixels 2wq, 2wq+1
        long base = ((long)(b * 128 + c) * 256 + 2 * h) * 64 + wq;
        float4 f0 = x4[base];
        float4 f1 = x4[base + 64];
        float p0 = (f0.x + f0.y + f1.x + f1.y) * 0.25f + sbias[c];
        float p1 = (f0.z + f0.w + f1.z + f1.w) * 0.25f + sbias[c];
        uint16_t v = (uint16_t)((p0 > 0.f ? 1u : 0u) | ((p1 > 0.f ? 1u : 0u) << 8));
        *reinterpret_cast<uint16_t*>(&sb[c * 132 + 2 * wq]) = v;
    }
    __syncthreads();
#pragma unroll
    for (int it = 0; it < 2; ++it) {
        int idx = it * 256 + tid;       // [0,512)
        int q = idx & 3;
        int w = idx >> 2;
        uint32_t word = 0;
#pragma unroll
        for (int i = 0; i < 32; ++i)
            word |= ((uint32_t)sb[(32 * q + i) * 132 + w]) << i;
        packedA[(((long)b * 128 + h) * 128 + w) * 4 + q] = word;
    }
}

// ---------------------------------------------------------------------------
// Kernel 2A: XNOR-popcount conv, 1 pixel/lane (v6, PROVEN — timing reference).
// Grid (64 hpair, 4 och, 8 b). Runs first; its output is overwritten by 2B.
// ---------------------------------------------------------------------------
#define PIN4(v) asm volatile("" : "+v"(v.x), "+v"(v.y), "+v"(v.z), "+v"(v.w))

__global__ __launch_bounds__(256, 4) void conv_kernel(const uint32_t* __restrict__ packedA,
                                                      const uint32_t* __restrict__ ocdata,
                                                      float* __restrict__ out) {
    int hp  = blockIdx.x;        // 0..63
    int och = blockIdx.y;        // 0..3 (64 oc each)
    int b   = blockIdx.z;
    int tid = threadIdx.x;

    __shared__ uint4 alds[4][132];      // rows 2hp-1..2hp+2, col idx = w+1
    const uint4* pa4 = reinterpret_cast<const uint4*>(packedA);
    for (int i = tid; i < 4 * 132; i += 256) {
        int r = i / 132, c = i % 132;
        int hh = 2 * hp - 1 + r;
        int col = c - 1;
        uint4 v = make_uint4(0u, 0u, 0u, 0u);
        if (col >= 0 && col < 128 && hh >= 0 && hh < 128)
            v = pa4[((b * 128 + hh) << 7) + col];
        alds[r][c] = v;
    }
    __syncthreads();

    int wv = tid >> 6, lane = tid & 63;
    int lr = wv >> 1;
    int cg = wv & 1;
    int row = 2 * hp + lr;
    int col = (cg << 6) + lane;

    uint4 A0 = alds[lr + 0][col + 0], A1 = alds[lr + 0][col + 1], A2 = alds[lr + 0][col + 2];
    uint4 A3 = alds[lr + 1][col + 0], A4 = alds[lr + 1][col + 1], A5 = alds[lr + 1][col + 2];
    uint4 A6 = alds[lr + 2][col + 0], A7 = alds[lr + 2][col + 1], A8 = alds[lr + 2][col + 2];
    PIN4(A0); PIN4(A1); PIN4(A2); PIN4(A3); PIN4(A4);
    PIN4(A5); PIN4(A6); PIN4(A7); PIN4(A8);

    bool top = (row == 0);
    bool bot = (row == 127);
    bool bl  = (col == 0);
    bool br  = (col == 127);

    int ocbase = och << 6;
    long obase = (((long)(b * 256 + ocbase) * 128 + row) << 7) + col;
    const uint32_t* od = ocdata + (size_t)ocbase * 56;

    for (int i = 0; i < 64; ++i, od += 56, obase += 16384) {
        const uint4* wt = reinterpret_cast<const uint4*>(od);
        uint4 w0 = wt[0], w1 = wt[1], w2 = wt[2], w3 = wt[3], w4 = wt[4];
        uint4 w5 = wt[5], w6 = wt[6], w7 = wt[7], w8 = wt[8];
        int acc = 0;
        acc += __builtin_popcount(A0.x ^ w0.x) + __builtin_popcount(A0.y ^ w0.y)
             + __builtin_popcount(A0.z ^ w0.z) + __builtin_popcount(A0.w ^ w0.w);
        acc += __builtin_popcount(A1.x ^ w1.x) + __builtin_popcount(A1.y ^ w1.y)
             + __builtin_popcount(A1.z ^ w1.z) + __builtin_popcount(A1.w ^ w1.w);
        acc += __builtin_popcount(A2.x ^ w2.x) + __builtin_popcount(A2.y ^ w2.y)
             + __builtin_popcount(A2.z ^ w2.z) + __builtin_popcount(A2.w ^ w2.w);
        acc += __builtin_popcount(A3.x ^ w3.x) + __builtin_popcount(A3.y ^ w3.y)
             + __builtin_popcount(A3.z ^ w3.z) + __builtin_popcount(A3.w ^ w3.w);
        acc += __builtin_popcount(A4.x ^ w4.x) + __builtin_popcount(A4.y ^ w4.y)
             + __builtin_popcount(A4.z ^ w4.z) + __builtin_popcount(A4.w ^ w4.w);
        acc += __builtin_popcount(A5.x ^ w5.x) + __builtin_popcount(A5.y ^ w5.y)
             + __builtin_popcount(A5.z ^ w5.z) + __builtin_popcount(A5.w ^ w5.w);
        acc += __builtin_popcount(A6.x ^ w6.x) + __builtin_popcount(A6.y ^ w6.y)
             + __builtin_popcount(A6.z ^ w6.z) + __builtin_popcount(A6.w ^ w6.w);
        acc += __builtin_popcount(A7.x ^ w7.x) + __builtin_popcount(A7.y ^ w7.y)
             + __builtin_popcount(A7.z ^ w7.z) + __builtin_popcount(A7.w ^ w7.w);
        acc += __builtin_popcount(A8.x ^ w8.x) + __builtin_popcount(A8.y ^ w8.y)
             + __builtin_popcount(A8.z ^ w8.z) + __builtin_popcount(A8.w ^ w8.w);

        int t0 = (int)od[36], t1 = (int)od[37], t2 = (int)od[38];
        int t3 = (int)od[39], t4 = (int)od[40], t5 = (int)od[41];
        int t6 = (int)od[42], t7 = (int)od[43], t8 = (int)od[44];
        int c0 = top ? t3 : (bot ? t6 : t0);
        int cL = top ? t4 : (bot ? t7 : t1);
        int cR = top ? t5 : (bot ? t8 : t2);
        int corr = bl ? cL : (br ? cR : c0);
        int tsum = 1152 - 2 * acc - corr;

        float s  = __uint_as_float(od[48]);
        float b0 = __uint_as_float(od[49]);
        float al = __uint_as_float(od[50]);
        float b1 = __uint_as_float(od[51]);
        float y = fmaf((float)tsum, s, b0);
        y = (y >= 0.f) ? y : al * y;
        out[obase] = y + b1;
    }
}

// ---------------------------------------------------------------------------
// Kernel 2B: XNOR-popcount conv, 2 ROWS PER LANE (hquad). Runs LAST (verified).
// Grid (32 hquad, 4 och, 8 b), 256 thr = 4 waves. Block covers rows
// 4hq..4hq+3 x 128 cols x 64 oc. Wave wv: lr=wv>>1 picks row-pair
// (r0=4hq+2lr, r1=r0+1), cg=wv&1 picks col half. Each lane computes the
// vertical pixel pair, so each 49-dword scalar record serves TWO pixels
// (half the per-pixel s_load traffic / loop / epilogue overhead) and the
// two popcount accumulation chains are INDEPENDENT (breaks the 36-deep
// dependent v_bcnt chain). Second store = first address + offset 512 B.
// A-window: 12 uint4 = 48 pinned VGPRs; weights stay SGPR (round-1 lesson).
// ---------------------------------------------------------------------------
__global__ __launch_bounds__(256, 4) void conv2_kernel(const uint32_t* __restrict__ packedA,
                                                       const uint32_t* __restrict__ ocdata,
                                                       float* __restrict__ out) {
    int hq  = blockIdx.x;        // 0..31
    int och = blockIdx.y;        // 0..3
    int b   = blockIdx.z;
    int tid = threadIdx.x;

    __shared__ uint4 alds[6][132];      // rows 4hq-1 .. 4hq+4, col idx = w+1
    const uint4* pa4 = reinterpret_cast<const uint4*>(packedA);
    for (int i = tid; i < 6 * 132; i += 256) {
        int r = i / 132, c = i % 132;
        int hh = 4 * hq - 1 + r;
        int col = c - 1;
        uint4 v = make_uint4(0u, 0u, 0u, 0u);
        if (col >= 0 && col < 128 && hh >= 0 && hh < 128)
            v = pa4[((b * 128 + hh) << 7) + col];
        alds[r][c] = v;
    }
    __syncthreads();

    int wv = tid >> 6, lane = tid & 63;
    int lr = wv >> 1;                   // row-pair select (0/1)
    int cg = wv & 1;                    // col half
    int r0 = 4 * hq + 2 * lr;           // even; r1 = r0+1 (odd)
    int col = (cg << 6) + lane;
    int lb = 2 * lr;                    // LDS row base: window rows lb..lb+3

    uint4 A0 = alds[lb + 0][col + 0], A1 = alds[lb + 0][col + 1], A2 = alds[lb + 0][col + 2];
    uint4 A3 = alds[lb + 1][col + 0], A4 = alds[lb + 1][col + 1], A5 = alds[lb + 1][col + 2];
    uint4 A6 = alds[lb + 2][col + 0], A7 = alds[lb + 2][col + 1], A8 = alds[lb + 2][col + 2];
    uint4 A9 = alds[lb + 3][col + 0], Aa = alds[lb + 3][col + 1], Ab = alds[lb + 3][col + 2];
    PIN4(A0); PIN4(A1); PIN4(A2); PIN4(A3); PIN4(A4); PIN4(A5);
    PIN4(A6); PIN4(A7); PIN4(A8); PIN4(A9); PIN4(Aa); PIN4(Ab);

    // r0 is even (never 127); r1 is odd (never 0).
    bool top0 = (r0 == 0);
    bool bot1 = (r0 == 126);            // r1 == 127
    bool bl   = (col == 0);
    bool br   = (col == 127);

    int ocbase = och << 6;
    long obase = (((long)(b * 256 + ocbase) * 128 + r0) << 7) + col;
    const uint32_t* od = ocdata + (size_t)ocbase * 56;

    for (int i = 0; i < 64; ++i, od += 56, obase += 16384) {
        const uint4* wt = reinterpret_cast<const uint4*>(od);
        uint4 w0 = wt[0], w1 = wt[1], w2 = wt[2], w3 = wt[3], w4 = wt[4];
        uint4 w5 = wt[5], w6 = wt[6], w7 = wt[7], w8 = wt[8];

        // pixel 0: rows lb..lb+2 (A0..A8);  pixel 1: rows lb+1..lb+3 (A3..Ab)
        int p = 0, q = 0;
        p += __builtin_popcount(A0.x ^ w0.x) + __builtin_popcount(A0.y ^ w0.y)
           + __builtin_popcount(A0.z ^ w0.z) + __builtin_popcount(A0.w ^ w0.w);
        q += __builtin_popcount(A3.x ^ w0.x) + __builtin_popcount(A3.y ^ w0.y)
           + __builtin_popcount(A3.z ^ w0.z) + __builtin_popcount(A3.w ^ w0.w);
        p += __builtin_popcount(A1.x ^ w1.x) + __builtin_popcount(A1.y ^ w1.y)
           + __builtin_popcount(A1.z ^ w1.z) + __builtin_popcount(A1.w ^ w1.w);
        q += __builtin_popcount(A4.x ^ w1.x) + __builtin_popcount(A4.y ^ w1.y)
           + __builtin_popcount(A4.z ^ w1.z) + __builtin_popcount(A4.w ^ w1.w);
        p += __builtin_popcount(A2.x ^ w2.x) + __builtin_popcount(A2.y ^ w2.y)
           + __builtin_popcount(A2.z ^ w2.z) + __builtin_popcount(A2.w ^ w2.w);
        q += __builtin_popcount(A5.x ^ w2.x) + __builtin_popcount(A5.y ^ w2.y)
           + __builtin_popcount(A5.z ^ w2.z) + __builtin_popcount(A5.w ^ w2.w);
        p += __builtin_popcount(A3.x ^ w3.x) + __builtin_popcount(A3.y ^ w3.y)
           + __builtin_popcount(A3.z ^ w3.z) + __builtin_popcount(A3.w ^ w3.w);
        q += __builtin_popcount(A6.x ^ w3.x) + __builtin_popcount(A6.y ^ w3.y)
           + __builtin_popcount(A6.z ^ w3.z) + __builtin_popcount(A6.w ^ w3.w);
        p += __builtin_popcount(A4.x ^ w4.x) + __builtin_popcount(A4.y ^ w4.y)
           + __builtin_popcount(A4.z ^ w4.z) + __builtin_popcount(A4.w ^ w4.w);
        q += __builtin_popcount(A7.x ^ w4.x) + __builtin_popcount(A7.y ^ w4.y)
           + __builtin_popcount(A7.z ^ w4.z) + __builtin_popcount(A7.w ^ w4.w);
        p += __builtin_popcount(A5.x ^ w5.x) + __builtin_popcount(A5.y ^ w5.y)
           + __builtin_popcount(A5.z ^ w5.z) + __builtin_popcount(A5.w ^ w5.w);
        q += __builtin_popcount(A8.x ^ w5.x) + __builtin_popcount(A8.y ^ w5.y)
           + __builtin_popcount(A8.z ^ w5.z) + __builtin_popcount(A8.w ^ w5.w);
        p += __builtin_popcount(A6.x ^ w6.x) + __builtin_popcount(A6.y ^ w6.y)
           + __builtin_popcount(A6.z ^ w6.z) + __builtin_popcount(A6.w ^ w6.w);
        q += __builtin_popcount(A9.x ^ w6.x) + __builtin_popcount(A9.y ^ w6.y)
           + __builtin_popcount(A9.z ^ w6.z) + __builtin_popcount(A9.w ^ w6.w);
        p += __builtin_popcount(A7.x ^ w7.x) + __builtin_popcount(A7.y ^ w7.y)
           + __builtin_popcount(A7.z ^ w7.z) + __builtin_popcount(A7.w ^ w7.w);
        q += __builtin_popcount(Aa.x ^ w7.x) + __builtin_popcount(Aa.y ^ w7.y)
           + __builtin_popcount(Aa.z ^ w7.z) + __builtin_popcount(Aa.w ^ w7.w);
        p += __builtin_popcount(A8.x ^ w8.x) + __builtin_popcount(A8.y ^ w8.y)
           + __builtin_popcount(A8.z ^ w8.z) + __builtin_popcount(A8.w ^ w8.w);
        q += __builtin_popcount(Ab.x ^ w8.x) + __builtin_popcount(Ab.y ^ w8.y)
           + __builtin_popcount(Ab.z ^ w8.z) + __builtin_popcount(Ab.w ^ w8.w);

        int t0 = (int)od[36], t1 = (int)od[37], t2 = (int)od[38];
        int t3 = (int)od[39], t4 = (int)od[40], t5 = (int)od[41];
        int t6 = (int)od[42], t7 = (int)od[43], t8 = (int)od[44];
        // pixel 0: top possible, bottom impossible
        int c00 = top0 ? t3 : t0;
        int cL0 = top0 ? t4 : t1;
        int cR0 = top0 ? t5 : t2;
        int corr0 = bl ? cL0 : (br ? cR0 : c00);
        // pixel 1: bottom possible, top impossible
        int c01 = bot1 ? t6 : t0;
        int cL1 = bot1 ? t7 : t1;
        int cR1 = bot1 ? t8 : t2;
        int corr1 = bl ? cL1 : (br ? cR1 : c01);

        int tsum0 = 1152 - 2 * p - corr0;
        int tsum1 = 1152 - 2 * q - corr1;

        float s  = __uint_as_float(od[48]);
        float b0 = __uint_as_float(od[49]);
        float al = __uint_as_float(od[50]);
        float b1 = __uint_as_float(od[51]);
        float y0 = fmaf((float)tsum0, s, b0);
        y0 = (y0 >= 0.f) ? y0 : al * y0;
        float y1 = fmaf((float)tsum1, s, b0);
        y1 = (y1 >= 0.f) ? y1 : al * y1;
        out[obase] = y0 + b1;
        out[obase + 128] = y1 + b1;     // row r0+1: +128 floats = offset 512 B
    }
}

// ---------------------------------------------------------------------------
extern "C" void kernel_launch(void* const* d_in, const int* in_sizes, int n_in,
                              void* d_out, int out_size, void* d_ws, size_t ws_size,
                              hipStream_t stream) {
    const float* x          = (const float*)d_in[0];  // (8,128,256,256)
    const float* weight     = (const float*)d_in[1];  // (256,128,3,3)
    const float* move0_bias = (const float*)d_in[2];  // 128
    const float* pb0        = (const float*)d_in[3];  // 256
    const float* alpha      = (const float*)d_in[4];  // 256
    const float* pb1        = (const float*)d_in[5];  // 256
    float* out = (float*)d_out;

    char* ws = (char*)d_ws;
    uint32_t* packedA = (uint32_t*)ws;                 // 2,097,152 B
    uint32_t* ocdata  = (uint32_t*)(ws + 2097152);     //    57,344 B

    wprep_kernel<<<256, 128, 0, stream>>>(weight, pb0, alpha, pb1, ocdata);
    pool_pack_kernel<<<dim3(128, 8), 256, 0, stream>>>(x, move0_bias, packedA);
    // A/B in one pass: A (proven v6) first, B (hquad) second. B overwrites
    // A's output, so correctness is verified on B; dur(B) = total - 494 (r5).
    conv_kernel<<<dim3(64, 4, 8), 256, 0, stream>>>(packedA, ocdata, out);
    conv2_kernel<<<dim3(32, 4, 8), 256, 0, stream>>>(packedA, ocdata, out);
}

// Round 7
// 487.917 us; speedup vs baseline: 1.2278x; 1.2278x over previous
//
#include <hip/hip_runtime.h>
#include <stdint.h>

// B=8, CIN=128, COUT=256, H=256, W=256 -> pooled 128x128, out (8,256,128,128) fp32

// Per-oc packed record in ocdata, stride 56 u32 (224 B):
//   [0..35]  packed weight bits: word (t*4+q) = bits of cin 32q..32q+31, tap t
//   [36..44] border corr (as int): case 3*hB+wB; hB 0/1(top)/2(bot), wB 0/1(L)/2(R)
//   [48]     scale, [49] pr_bias0, [50] alpha, [51] pr_bias1  (floats)

// ---------------------------------------------------------------------------
// Kernel 0: weight prep. One block per output channel (256 blocks, 128 thr).
// ---------------------------------------------------------------------------
__global__ __launch_bounds__(128) void wprep_kernel(const float* __restrict__ w,
                                                    const float* __restrict__ pb0,
                                                    const float* __restrict__ alpha,
                                                    const float* __restrict__ pb1,
                                                    uint32_t* __restrict__ ocdata) {
    int oc = blockIdx.x;
    int cin = threadIdx.x;              // 0..127
    const float* wp = w + ((long)oc * 128 + cin) * 9;
    float wk[9];
    float sabs = 0.f;
#pragma unroll
    for (int k = 0; k < 9; ++k) { wk[k] = wp[k]; sabs += fabsf(wk[k]); }
    int gi = cin >> 6;                  // wave id 0/1
    int lane = cin & 63;
    __shared__ float ssum[2];
    __shared__ int spc[2][9];
    for (int off = 32; off > 0; off >>= 1) sabs += __shfl_down(sabs, off, 64);
    if (lane == 0) ssum[gi] = sabs;
    uint32_t* od = ocdata + (size_t)oc * 56;
#pragma unroll
    for (int k = 0; k < 9; ++k) {
        unsigned long long m = __ballot(wk[k] > 0.f);
        if (lane == 0) {
            od[k * 4 + 2 * gi]     = (uint32_t)m;
            od[k * 4 + 2 * gi + 1] = (uint32_t)(m >> 32);
            spc[gi][k] = __popcll(m);
        }
    }
    __syncthreads();
    if (cin == 0) {
        float s = (ssum[0] + ssum[1]) * (1.0f / 1152.0f);
        od[48] = __float_as_uint(s);
        od[49] = __float_as_uint(pb0[oc]);
        od[50] = __float_as_uint(alpha[oc]);
        od[51] = __float_as_uint(pb1[oc]);
        int ct[9];
#pragma unroll
        for (int t = 0; t < 9; ++t) ct[t] = 128 - 2 * (spc[0][t] + spc[1][t]);
        int cT = ct[0] + ct[1] + ct[2];
        int cB = ct[6] + ct[7] + ct[8];
        int cL = ct[0] + ct[3] + ct[6];
        int cR = ct[2] + ct[5] + ct[8];
        od[36 + 0] = (uint32_t)0;                       // interior
        od[36 + 1] = (uint32_t)cL;                      // left
        od[36 + 2] = (uint32_t)cR;                      // right
        od[36 + 3] = (uint32_t)cT;                      // top
        od[36 + 4] = (uint32_t)(cT + cL - ct[0]);       // top-left
        od[36 + 5] = (uint32_t)(cT + cR - ct[2]);       // top-right
        od[36 + 6] = (uint32_t)cB;                      // bottom
        od[36 + 7] = (uint32_t)(cB + cL - ct[6]);       // bottom-left
        od[36 + 8] = (uint32_t)(cB + cR - ct[8]);       // bottom-right
        od[45] = od[46] = od[47] = 0u;
        od[52] = od[53] = od[54] = od[55] = 0u;
    }
}

// ---------------------------------------------------------------------------
// Kernel 1: avgpool 2x2 + bias + sign -> channel-bit-packed activations.
// ---------------------------------------------------------------------------
__global__ __launch_bounds__(256) void pool_pack_kernel(const float* __restrict__ x,
                                                        const float* __restrict__ bias,
                                                        uint32_t* __restrict__ packedA) {
    int h = blockIdx.x;    // pooled row 0..127
    int b = blockIdx.y;    // 0..7
    int tid = threadIdx.x;
    __shared__ float sbias[128];
    __shared__ uint8_t sb[128 * 132];   // [c][w] bytes, row stride 132
    if (tid < 128) sbias[tid] = bias[tid];
    __syncthreads();
    const float4* x4 = reinterpret_cast<const float4*>(x);
#pragma unroll 4
    for (int it = 0; it < 32; ++it) {
        int j = it * 256 + tid;         // [0, 8192)
        int c = j >> 6;                 // 0..127
        int wq = j & 63;                // float4 col -> output pixels 2wq, 2wq+1
        long base = ((long)(b * 128 + c) * 256 + 2 * h) * 64 + wq;
        float4 f0 = x4[base];
        float4 f1 = x4[base + 64];
        float p0 = (f0.x + f0.y + f1.x + f1.y) * 0.25f + sbias[c];
        float p1 = (f0.z + f0.w + f1.z + f1.w) * 0.25f + sbias[c];
        uint16_t v = (uint16_t)((p0 > 0.f ? 1u : 0u) | ((p1 > 0.f ? 1u : 0u) << 8));
        *reinterpret_cast<uint16_t*>(&sb[c * 132 + 2 * wq]) = v;
    }
    __syncthreads();
#pragma unroll
    for (int it = 0; it < 2; ++it) {
        int idx = it * 256 + tid;       // [0,512)
        int q = idx & 3;
        int w = idx >> 2;
        uint32_t word = 0;
#pragma unroll
        for (int i = 0; i < 32; ++i)
            word |= ((uint32_t)sb[(32 * q + i) * 132 + w]) << i;
        packedA[(((long)b * 128 + h) * 128 + w) * 4 + q] = word;
    }
}

// ---------------------------------------------------------------------------
// Kernel 2: XNOR-popcount conv, 2 ROWS PER LANE, och split 8.
// Grid (32 hquad, 8 och-eighth, 8 b) = 2048 blocks, 256 thr = 4 waves.
//
// v8: occupancy probe. Differential timing (F = 380.8 µs fixed overhead,
// calibrated r1/r2/r5/r6) shows conv2 = 105 µs vs ~35 µs VALU floor with
// SIMD issue-busy ~34%. Eliminated so far: vL1 thrash (r1), vmcnt
// store-drain (r5), scalar-load volume / bcnt dep chains (r6 — 2-row split
// gained only 8 µs). Remaining suspect: grid gave exactly 4 blocks/CU =
// 4 waves/SIMD (grid-limited, not reg/LDS-limited); barrier-started
// lockstep waves can't cover per-iteration scalar-record miss latency.
// Fix: och 4->8 (32-oc records, 7.2 KB, grid 2048) + __launch_bounds__
// (256,6) -> VGPR cap 85 (body needs ~70; NOT the 64-cap of (256,8) —
// round-1 spill lesson) -> 6 blocks/CU = 24 waves/CU, 1.5x hiding.
// Inner loop byte-identical to r6's conv2.
// ---------------------------------------------------------------------------
#define PIN4(v) asm volatile("" : "+v"(v.x), "+v"(v.y), "+v"(v.z), "+v"(v.w))

__global__ __launch_bounds__(256, 6) void conv2_kernel(const uint32_t* __restrict__ packedA,
                                                       const uint32_t* __restrict__ ocdata,
                                                       float* __restrict__ out) {
    int hq  = blockIdx.x;        // 0..31
    int och = blockIdx.y;        // 0..7 (32 oc each)
    int b   = blockIdx.z;
    int tid = threadIdx.x;

    __shared__ uint4 alds[6][132];      // rows 4hq-1 .. 4hq+4, col idx = w+1
    const uint4* pa4 = reinterpret_cast<const uint4*>(packedA);
    for (int i = tid; i < 6 * 132; i += 256) {
        int r = i / 132, c = i % 132;
        int hh = 4 * hq - 1 + r;
        int col = c - 1;
        uint4 v = make_uint4(0u, 0u, 0u, 0u);
        if (col >= 0 && col < 128 && hh >= 0 && hh < 128)
            v = pa4[((b * 128 + hh) << 7) + col];
        alds[r][c] = v;
    }
    __syncthreads();

    int wv = tid >> 6, lane = tid & 63;
    int lr = wv >> 1;                   // row-pair select (0/1)
    int cg = wv & 1;                    // col half
    int r0 = 4 * hq + 2 * lr;           // even; r1 = r0+1 (odd)
    int col = (cg << 6) + lane;
    int lb = 2 * lr;                    // LDS row base: window rows lb..lb+3

    uint4 A0 = alds[lb + 0][col + 0], A1 = alds[lb + 0][col + 1], A2 = alds[lb + 0][col + 2];
    uint4 A3 = alds[lb + 1][col + 0], A4 = alds[lb + 1][col + 1], A5 = alds[lb + 1][col + 2];
    uint4 A6 = alds[lb + 2][col + 0], A7 = alds[lb + 2][col + 1], A8 = alds[lb + 2][col + 2];
    uint4 A9 = alds[lb + 3][col + 0], Aa = alds[lb + 3][col + 1], Ab = alds[lb + 3][col + 2];
    PIN4(A0); PIN4(A1); PIN4(A2); PIN4(A3); PIN4(A4); PIN4(A5);
    PIN4(A6); PIN4(A7); PIN4(A8); PIN4(A9); PIN4(Aa); PIN4(Ab);

    // r0 is even (never 127); r1 is odd (never 0).
    bool top0 = (r0 == 0);
    bool bot1 = (r0 == 126);            // r1 == 127
    bool bl   = (col == 0);
    bool br   = (col == 127);

    int ocbase = och << 5;
    long obase = (((long)(b * 256 + ocbase) * 128 + r0) << 7) + col;
    const uint32_t* od = ocdata + (size_t)ocbase * 56;

    for (int i = 0; i < 32; ++i, od += 56, obase += 16384) {
        const uint4* wt = reinterpret_cast<const uint4*>(od);
        uint4 w0 = wt[0], w1 = wt[1], w2 = wt[2], w3 = wt[3], w4 = wt[4];
        uint4 w5 = wt[5], w6 = wt[6], w7 = wt[7], w8 = wt[8];

        // pixel 0: rows lb..lb+2 (A0..A8);  pixel 1: rows lb+1..lb+3 (A3..Ab)
        int p = 0, q = 0;
        p += __builtin_popcount(A0.x ^ w0.x) + __builtin_popcount(A0.y ^ w0.y)
           + __builtin_popcount(A0.z ^ w0.z) + __builtin_popcount(A0.w ^ w0.w);
        q += __builtin_popcount(A3.x ^ w0.x) + __builtin_popcount(A3.y ^ w0.y)
           + __builtin_popcount(A3.z ^ w0.z) + __builtin_popcount(A3.w ^ w0.w);
        p += __builtin_popcount(A1.x ^ w1.x) + __builtin_popcount(A1.y ^ w1.y)
           + __builtin_popcount(A1.z ^ w1.z) + __builtin_popcount(A1.w ^ w1.w);
        q += __builtin_popcount(A4.x ^ w1.x) + __builtin_popcount(A4.y ^ w1.y)
           + __builtin_popcount(A4.z ^ w1.z) + __builtin_popcount(A4.w ^ w1.w);
        p += __builtin_popcount(A2.x ^ w2.x) + __builtin_popcount(A2.y ^ w2.y)
           + __builtin_popcount(A2.z ^ w2.z) + __builtin_popcount(A2.w ^ w2.w);
        q += __builtin_popcount(A5.x ^ w2.x) + __builtin_popcount(A5.y ^ w2.y)
           + __builtin_popcount(A5.z ^ w2.z) + __builtin_popcount(A5.w ^ w2.w);
        p += __builtin_popcount(A3.x ^ w3.x) + __builtin_popcount(A3.y ^ w3.y)
           + __builtin_popcount(A3.z ^ w3.z) + __builtin_popcount(A3.w ^ w3.w);
        q += __builtin_popcount(A6.x ^ w3.x) + __builtin_popcount(A6.y ^ w3.y)
           + __builtin_popcount(A6.z ^ w3.z) + __builtin_popcount(A6.w ^ w3.w);
        p += __builtin_popcount(A4.x ^ w4.x) + __builtin_popcount(A4.y ^ w4.y)
           + __builtin_popcount(A4.z ^ w4.z) + __builtin_popcount(A4.w ^ w4.w);
        q += __builtin_popcount(A7.x ^ w4.x) + __builtin_popcount(A7.y ^ w4.y)
           + __builtin_popcount(A7.z ^ w4.z) + __builtin_popcount(A7.w ^ w4.w);
        p += __builtin_popcount(A5.x ^ w5.x) + __builtin_popcount(A5.y ^ w5.y)
           + __builtin_popcount(A5.z ^ w5.z) + __builtin_popcount(A5.w ^ w5.w);
        q += __builtin_popcount(A8.x ^ w5.x) + __builtin_popcount(A8.y ^ w5.y)
           + __builtin_popcount(A8.z ^ w5.z) + __builtin_popcount(A8.w ^ w5.w);
        p += __builtin_popcount(A6.x ^ w6.x) + __builtin_popcount(A6.y ^ w6.y)
           + __builtin_popcount(A6.z ^ w6.z) + __builtin_popcount(A6.w ^ w6.w);
        q += __builtin_popcount(A9.x ^ w6.x) + __builtin_popcount(A9.y ^ w6.y)
           + __builtin_popcount(A9.z ^ w6.z) + __builtin_popcount(A9.w ^ w6.w);
        p += __builtin_popcount(A7.x ^ w7.x) + __builtin_popcount(A7.y ^ w7.y)
           + __builtin_popcount(A7.z ^ w7.z) + __builtin_popcount(A7.w ^ w7.w);
        q += __builtin_popcount(Aa.x ^ w7.x) + __builtin_popcount(Aa.y ^ w7.y)
           + __builtin_popcount(Aa.z ^ w7.z) + __builtin_popcount(Aa.w ^ w7.w);
        p += __builtin_popcount(A8.x ^ w8.x) + __builtin_popcount(A8.y ^ w8.y)
           + __builtin_popcount(A8.z ^ w8.z) + __builtin_popcount(A8.w ^ w8.w);
        q += __builtin_popcount(Ab.x ^ w8.x) + __builtin_popcount(Ab.y ^ w8.y)
           + __builtin_popcount(Ab.z ^ w8.z) + __builtin_popcount(Ab.w ^ w8.w);

        int t0 = (int)od[36], t1 = (int)od[37], t2 = (int)od[38];
        int t3 = (int)od[39], t4 = (int)od[40], t5 = (int)od[41];
        int t6 = (int)od[42], t7 = (int)od[43], t8 = (int)od[44];
        // pixel 0: top possible, bottom impossible
        int c00 = top0 ? t3 : t0;
        int cL0 = top0 ? t4 : t1;
        int cR0 = top0 ? t5 : t2;
        int corr0 = bl ? cL0 : (br ? cR0 : c00);
        // pixel 1: bottom possible, top impossible
        int c01 = bot1 ? t6 : t0;
        int cL1 = bot1 ? t7 : t1;
        int cR1 = bot1 ? t8 : t2;
        int corr1 = bl ? cL1 : (br ? cR1 : c01);

        int tsum0 = 1152 - 2 * p - corr0;
        int tsum1 = 1152 - 2 * q - corr1;

        float s  = __uint_as_float(od[48]);
        float b0 = __uint_as_float(od[49]);
        float al = __uint_as_float(od[50]);
        float b1 = __uint_as_float(od[51]);
        float y0 = fmaf((float)tsum0, s, b0);
        y0 = (y0 >= 0.f) ? y0 : al * y0;
        float y1 = fmaf((float)tsum1, s, b0);
        y1 = (y1 >= 0.f) ? y1 : al * y1;
        out[obase] = y0 + b1;
        out[obase + 128] = y1 + b1;     // row r0+1: +128 floats = offset 512 B
    }
}

// ---------------------------------------------------------------------------
extern "C" void kernel_launch(void* const* d_in, const int* in_sizes, int n_in,
                              void* d_out, int out_size, void* d_ws, size_t ws_size,
                              hipStream_t stream) {
    const float* x          = (const float*)d_in[0];  // (8,128,256,256)
    const float* weight     = (const float*)d_in[1];  // (256,128,3,3)
    const float* move0_bias = (const float*)d_in[2];  // 128
    const float* pb0        = (const float*)d_in[3];  // 256
    const float* alpha      = (const float*)d_in[4];  // 256
    const float* pb1        = (const float*)d_in[5];  // 256
    float* out = (float*)d_out;

    char* ws = (char*)d_ws;
    uint32_t* packedA = (uint32_t*)ws;                 // 2,097,152 B
    uint32_t* ocdata  = (uint32_t*)(ws + 2097152);     //    57,344 B

    wprep_kernel<<<256, 128, 0, stream>>>(weight, pb0, alpha, pb1, ocdata);
    pool_pack_kernel<<<dim3(128, 8), 256, 0, stream>>>(x, move0_bias, packedA);
    conv2_kernel<<<dim3(32, 8, 8), 256, 0, stream>>>(packedA, ocdata, out);
}

// Round 8
// 484.845 us; speedup vs baseline: 1.2356x; 1.0063x over previous
//
#include <hip/hip_runtime.h>
#include <stdint.h>

// B=8, CIN=128, COUT=256, H=256, W=256 -> pooled 128x128, out (8,256,128,128) fp32

// Per-oc packed record in ocdata, stride 56 u32 (224 B):
//   [0..35]  packed weight bits: word (t*4+q) = bits of cin 32q..32q+31, tap t
//   [36..44] border corr (as int): case 3*hB+wB; hB 0/1(top)/2(bot), wB 0/1(L)/2(R)
//   [48]     scale, [49] pr_bias0, [50] alpha, [51] pr_bias1  (floats)

// ---------------------------------------------------------------------------
// Kernel 0: weight prep. One block per output channel (256 blocks, 128 thr).
// ---------------------------------------------------------------------------
__global__ __launch_bounds__(128) void wprep_kernel(const float* __restrict__ w,
                                                    const float* __restrict__ pb0,
                                                    const float* __restrict__ alpha,
                                                    const float* __restrict__ pb1,
                                                    uint32_t* __restrict__ ocdata) {
    int oc = blockIdx.x;
    int cin = threadIdx.x;              // 0..127
    const float* wp = w + ((long)oc * 128 + cin) * 9;
    float wk[9];
    float sabs = 0.f;
#pragma unroll
    for (int k = 0; k < 9; ++k) { wk[k] = wp[k]; sabs += fabsf(wk[k]); }
    int gi = cin >> 6;                  // wave id 0/1
    int lane = cin & 63;
    __shared__ float ssum[2];
    __shared__ int spc[2][9];
    for (int off = 32; off > 0; off >>= 1) sabs += __shfl_down(sabs, off, 64);
    if (lane == 0) ssum[gi] = sabs;
    uint32_t* od = ocdata + (size_t)oc * 56;
#pragma unroll
    for (int k = 0; k < 9; ++k) {
        unsigned long long m = __ballot(wk[k] > 0.f);
        if (lane == 0) {
            od[k * 4 + 2 * gi]     = (uint32_t)m;
            od[k * 4 + 2 * gi + 1] = (uint32_t)(m >> 32);
            spc[gi][k] = __popcll(m);
        }
    }
    __syncthreads();
    if (cin == 0) {
        float s = (ssum[0] + ssum[1]) * (1.0f / 1152.0f);
        od[48] = __float_as_uint(s);
        od[49] = __float_as_uint(pb0[oc]);
        od[50] = __float_as_uint(alpha[oc]);
        od[51] = __float_as_uint(pb1[oc]);
        int ct[9];
#pragma unroll
        for (int t = 0; t < 9; ++t) ct[t] = 128 - 2 * (spc[0][t] + spc[1][t]);
        int cT = ct[0] + ct[1] + ct[2];
        int cB = ct[6] + ct[7] + ct[8];
        int cL = ct[0] + ct[3] + ct[6];
        int cR = ct[2] + ct[5] + ct[8];
        od[36 + 0] = (uint32_t)0;                       // interior
        od[36 + 1] = (uint32_t)cL;                      // left
        od[36 + 2] = (uint32_t)cR;                      // right
        od[36 + 3] = (uint32_t)cT;                      // top
        od[36 + 4] = (uint32_t)(cT + cL - ct[0]);       // top-left
        od[36 + 5] = (uint32_t)(cT + cR - ct[2]);       // top-right
        od[36 + 6] = (uint32_t)cB;                      // bottom
        od[36 + 7] = (uint32_t)(cB + cL - ct[6]);       // bottom-left
        od[36 + 8] = (uint32_t)(cB + cR - ct[8]);       // bottom-right
        od[45] = od[46] = od[47] = 0u;
        od[52] = od[53] = od[54] = od[55] = 0u;
    }
}

// ---------------------------------------------------------------------------
// Kernel 1: avgpool 2x2 + bias + sign -> channel-bit-packed activations.
// ---------------------------------------------------------------------------
__global__ __launch_bounds__(256) void pool_pack_kernel(const float* __restrict__ x,
                                                        const float* __restrict__ bias,
                                                        uint32_t* __restrict__ packedA) {
    int h = blockIdx.x;    // pooled row 0..127
    int b = blockIdx.y;    // 0..7
    int tid = threadIdx.x;
    __shared__ float sbias[128];
    __shared__ uint8_t sb[128 * 132];   // [c][w] bytes, row stride 132
    if (tid < 128) sbias[tid] = bias[tid];
    __syncthreads();
    const float4* x4 = reinterpret_cast<const float4*>(x);
#pragma unroll 4
    for (int it = 0; it < 32; ++it) {
        int j = it * 256 + tid;         // [0, 8192)
        int c = j >> 6;                 // 0..127
        int wq = j & 63;                // float4 col -> output pixels 2wq, 2wq+1
        long base = ((long)(b * 128 + c) * 256 + 2 * h) * 64 + wq;
        float4 f0 = x4[base];
        float4 f1 = x4[base + 64];
        float p0 = (f0.x + f0.y + f1.x + f1.y) * 0.25f + sbias[c];
        float p1 = (f0.z + f0.w + f1.z + f1.w) * 0.25f + sbias[c];
        uint16_t v = (uint16_t)((p0 > 0.f ? 1u : 0u) | ((p1 > 0.f ? 1u : 0u) << 8));
        *reinterpret_cast<uint16_t*>(&sb[c * 132 + 2 * wq]) = v;
    }
    __syncthreads();
#pragma unroll
    for (int it = 0; it < 2; ++it) {
        int idx = it * 256 + tid;       // [0,512)
        int q = idx & 3;
        int w = idx >> 2;
        uint32_t word = 0;
#pragma unroll
        for (int i = 0; i < 32; ++i)
            word |= ((uint32_t)sb[(32 * q + i) * 132 + w]) << i;
        packedA[(((long)b * 128 + h) * 128 + w) * 4 + q] = word;
    }
}

// ---------------------------------------------------------------------------
// Kernel 2: XNOR-popcount conv, 2 rows/lane, FUSED bcnt-accumulate.
// Grid (32 hquad, 4 och, 8 b) = 1024 blocks, 256 thr = 4 waves (r6 config,
// best known: 105 µs; r7's och8/6-blocks variant was flat -> reverted).
//
// v9: cross-round analysis shows a constant ~5.3 cyc/inst instruction-
// throughput wall (occupancy-insensitive at 4/6/8 waves/SIMD; time tracks
// inst count). Suspect: compiler emits v_bcnt + SEPARATE v_add instead of
// v_bcnt_u32_b32's hardware-fused accumulate (D = bcnt(S0)+S1), i.e. the
// core is ~250 insts not ~180. Fix: force the fused form with non-volatile
// 2-operand inline asm (pure dataflow, compiler can still schedule).
// Removes ~71 adds/iter (-28% inst count) if the hypothesis holds.
// ---------------------------------------------------------------------------
#define PIN4(v) asm volatile("" : "+v"(v.x), "+v"(v.y), "+v"(v.z), "+v"(v.w))
// acc = popcount(x) + acc, single instruction.
#define XB(ACC, AV, WV) { uint32_t _x = (AV) ^ (WV); \
    asm("v_bcnt_u32_b32 %0, %1, %0" : "+v"(ACC) : "v"(_x)); }

__global__ __launch_bounds__(256, 4) void conv2_kernel(const uint32_t* __restrict__ packedA,
                                                       const uint32_t* __restrict__ ocdata,
                                                       float* __restrict__ out) {
    int hq  = blockIdx.x;        // 0..31
    int och = blockIdx.y;        // 0..3 (64 oc each)
    int b   = blockIdx.z;
    int tid = threadIdx.x;

    __shared__ uint4 alds[6][132];      // rows 4hq-1 .. 4hq+4, col idx = w+1
    const uint4* pa4 = reinterpret_cast<const uint4*>(packedA);
    for (int i = tid; i < 6 * 132; i += 256) {
        int r = i / 132, c = i % 132;
        int hh = 4 * hq - 1 + r;
        int col = c - 1;
        uint4 v = make_uint4(0u, 0u, 0u, 0u);
        if (col >= 0 && col < 128 && hh >= 0 && hh < 128)
            v = pa4[((b * 128 + hh) << 7) + col];
        alds[r][c] = v;
    }
    __syncthreads();

    int wv = tid >> 6, lane = tid & 63;
    int lr = wv >> 1;                   // row-pair select (0/1)
    int cg = wv & 1;                    // col half
    int r0 = 4 * hq + 2 * lr;           // even; r1 = r0+1 (odd)
    int col = (cg << 6) + lane;
    int lb = 2 * lr;                    // LDS row base: window rows lb..lb+3

    uint4 A0 = alds[lb + 0][col + 0], A1 = alds[lb + 0][col + 1], A2 = alds[lb + 0][col + 2];
    uint4 A3 = alds[lb + 1][col + 0], A4 = alds[lb + 1][col + 1], A5 = alds[lb + 1][col + 2];
    uint4 A6 = alds[lb + 2][col + 0], A7 = alds[lb + 2][col + 1], A8 = alds[lb + 2][col + 2];
    uint4 A9 = alds[lb + 3][col + 0], Aa = alds[lb + 3][col + 1], Ab = alds[lb + 3][col + 2];
    PIN4(A0); PIN4(A1); PIN4(A2); PIN4(A3); PIN4(A4); PIN4(A5);
    PIN4(A6); PIN4(A7); PIN4(A8); PIN4(A9); PIN4(Aa); PIN4(Ab);

    // r0 is even (never 127); r1 is odd (never 0).
    bool top0 = (r0 == 0);
    bool bot1 = (r0 == 126);            // r1 == 127
    bool bl   = (col == 0);
    bool br   = (col == 127);

    int ocbase = och << 6;
    long obase = (((long)(b * 256 + ocbase) * 128 + r0) << 7) + col;
    const uint32_t* od = ocdata + (size_t)ocbase * 56;

    for (int i = 0; i < 64; ++i, od += 56, obase += 16384) {
        const uint4* wt = reinterpret_cast<const uint4*>(od);
        uint4 w0 = wt[0], w1 = wt[1], w2 = wt[2], w3 = wt[3], w4 = wt[4];
        uint4 w5 = wt[5], w6 = wt[6], w7 = wt[7], w8 = wt[8];

        // pixel 0: rows lb..lb+2 (A0..A8);  pixel 1: rows lb+1..lb+3 (A3..Ab)
        uint32_t p = 0, q = 0;
        XB(p, A0.x, w0.x); XB(p, A0.y, w0.y); XB(p, A0.z, w0.z); XB(p, A0.w, w0.w);
        XB(q, A3.x, w0.x); XB(q, A3.y, w0.y); XB(q, A3.z, w0.z); XB(q, A3.w, w0.w);
        XB(p, A1.x, w1.x); XB(p, A1.y, w1.y); XB(p, A1.z, w1.z); XB(p, A1.w, w1.w);
        XB(q, A4.x, w1.x); XB(q, A4.y, w1.y); XB(q, A4.z, w1.z); XB(q, A4.w, w1.w);
        XB(p, A2.x, w2.x); XB(p, A2.y, w2.y); XB(p, A2.z, w2.z); XB(p, A2.w, w2.w);
        XB(q, A5.x, w2.x); XB(q, A5.y, w2.y); XB(q, A5.z, w2.z); XB(q, A5.w, w2.w);
        XB(p, A3.x, w3.x); XB(p, A3.y, w3.y); XB(p, A3.z, w3.z); XB(p, A3.w, w3.w);
        XB(q, A6.x, w3.x); XB(q, A6.y, w3.y); XB(q, A6.z, w3.z); XB(q, A6.w, w3.w);
        XB(p, A4.x, w4.x); XB(p, A4.y, w4.y); XB(p, A4.z, w4.z); XB(p, A4.w, w4.w);
        XB(q, A7.x, w4.x); XB(q, A7.y, w4.y); XB(q, A7.z, w4.z); XB(q, A7.w, w4.w);
        XB(p, A5.x, w5.x); XB(p, A5.y, w5.y); XB(p, A5.z, w5.z); XB(p, A5.w, w5.w);
        XB(q, A8.x, w5.x); XB(q, A8.y, w5.y); XB(q, A8.z, w5.z); XB(q, A8.w, w5.w);
        XB(p, A6.x, w6.x); XB(p, A6.y, w6.y); XB(p, A6.z, w6.z); XB(p, A6.w, w6.w);
        XB(q, A9.x, w6.x); XB(q, A9.y, w6.y); XB(q, A9.z, w6.z); XB(q, A9.w, w6.w);
        XB(p, A7.x, w7.x); XB(p, A7.y, w7.y); XB(p, A7.z, w7.z); XB(p, A7.w, w7.w);
        XB(q, Aa.x, w7.x); XB(q, Aa.y, w7.y); XB(q, Aa.z, w7.z); XB(q, Aa.w, w7.w);
        XB(p, A8.x, w8.x); XB(p, A8.y, w8.y); XB(p, A8.z, w8.z); XB(p, A8.w, w8.w);
        XB(q, Ab.x, w8.x); XB(q, Ab.y, w8.y); XB(q, Ab.z, w8.z); XB(q, Ab.w, w8.w);

        int t0 = (int)od[36], t1 = (int)od[37], t2 = (int)od[38];
        int t3 = (int)od[39], t4 = (int)od[40], t5 = (int)od[41];
        int t6 = (int)od[42], t7 = (int)od[43], t8 = (int)od[44];
        // pixel 0: top possible, bottom impossible
        int c00 = top0 ? t3 : t0;
        int cL0 = top0 ? t4 : t1;
        int cR0 = top0 ? t5 : t2;
        int corr0 = bl ? cL0 : (br ? cR0 : c00);
        // pixel 1: bottom possible, top impossible
        int c01 = bot1 ? t6 : t0;
        int cL1 = bot1 ? t7 : t1;
        int cR1 = bot1 ? t8 : t2;
        int corr1 = bl ? cL1 : (br ? cR1 : c01);

        int tsum0 = 1152 - 2 * (int)p - corr0;
        int tsum1 = 1152 - 2 * (int)q - corr1;

        float s  = __uint_as_float(od[48]);
        float b0 = __uint_as_float(od[49]);
        float al = __uint_as_float(od[50]);
        float b1 = __uint_as_float(od[51]);
        float y0 = fmaf((float)tsum0, s, b0);
        y0 = (y0 >= 0.f) ? y0 : al * y0;
        float y1 = fmaf((float)tsum1, s, b0);
        y1 = (y1 >= 0.f) ? y1 : al * y1;
        out[obase] = y0 + b1;
        out[obase + 128] = y1 + b1;     // row r0+1: +128 floats = offset 512 B
    }
}

// ---------------------------------------------------------------------------
extern "C" void kernel_launch(void* const* d_in, const int* in_sizes, int n_in,
                              void* d_out, int out_size, void* d_ws, size_t ws_size,
                              hipStream_t stream) {
    const float* x          = (const float*)d_in[0];  // (8,128,256,256)
    const float* weight     = (const float*)d_in[1];  // (256,128,3,3)
    const float* move0_bias = (const float*)d_in[2];  // 128
    const float* pb0        = (const float*)d_in[3];  // 256
    const float* alpha      = (const float*)d_in[4];  // 256
    const float* pb1        = (const float*)d_in[5];  // 256
    float* out = (float*)d_out;

    char* ws = (char*)d_ws;
    uint32_t* packedA = (uint32_t*)ws;                 // 2,097,152 B
    uint32_t* ocdata  = (uint32_t*)(ws + 2097152);     //    57,344 B

    wprep_kernel<<<256, 128, 0, stream>>>(weight, pb0, alpha, pb1, ocdata);
    pool_pack_kernel<<<dim3(128, 8), 256, 0, stream>>>(x, move0_bias, packedA);
    conv2_kernel<<<dim3(32, 4, 8), 256, 0, stream>>>(packedA, ocdata, out);
}